// Round 1
// baseline (4083.698 us; speedup 1.0000x reference)
//
#include <hip/hip_runtime.h>
#include <hip/hip_bf16.h>

#define BB 128
#define TT 2048
#define HH 64
#define EPS_BN 1e-5f

__device__ __forceinline__ float gelu_exact(float x) {
    return 0.5f * x * (1.0f + erff(x * 0.70710678118654752440f));
}
__device__ __forceinline__ float sigm(float x) { return 1.0f / (1.0f + __expf(-x)); }
__device__ __forceinline__ float tanh_(float x) {
    float e = __expf(2.0f * x);
    return 1.0f - 2.0f / (e + 1.0f);
}
__device__ __forceinline__ float lse2(float a, float b) {
    float m = fmaxf(a, b);
    return m + log1pf(__expf(-fabsf(a - b)));
}

// ---------------- conv stack: 2->64 (GELU,BN) then 3x 64->64 (GELU,BN) ----------------
__device__ __forceinline__ void layer64(const float* __restrict__ in, float* __restrict__ out,
                                        const float* __restrict__ w, const float* __restrict__ bvec,
                                        const float* __restrict__ sc, const float* __restrict__ sh) {
#pragma unroll
    for (int j = 0; j < HH; ++j) {
        float acc = bvec[j];
        const float4* w4 = (const float4*)(w + j * HH);
#pragma unroll
        for (int k4 = 0; k4 < 16; ++k4) {
            float4 wv = w4[k4];
            acc += wv.x * in[4 * k4] + wv.y * in[4 * k4 + 1] + wv.z * in[4 * k4 + 2] + wv.w * in[4 * k4 + 3];
        }
        float t = gelu_exact(acc);
        out[j] = t * sc[j] + sh[j];
    }
}

__global__ __launch_bounds__(256) void conv_kernel(
    const float* __restrict__ x, const float* __restrict__ cw1, const float* __restrict__ cb1,
    const float* __restrict__ cwr, const float* __restrict__ cbr,
    const float* __restrict__ bn_g, const float* __restrict__ bn_b,
    const float* __restrict__ bn_m, const float* __restrict__ bn_v,
    float* __restrict__ y) {
    __shared__ float s_w1[HH * 2];
    __shared__ float s_b1[HH];
    __shared__ float s_w[3][HH * HH];
    __shared__ float s_b[3][HH];
    __shared__ float s_scale[4][HH];
    __shared__ float s_shift[4][HH];
    int tid = threadIdx.x;
    for (int i = tid; i < HH * 2; i += 256) s_w1[i] = cw1[i];
    if (tid < HH) s_b1[tid] = cb1[tid];
    for (int i = tid; i < 3 * HH * HH; i += 256) (&s_w[0][0])[i] = cwr[i];
    for (int i = tid; i < 3 * HH; i += 256) (&s_b[0][0])[i] = cbr[i];
    if (tid < 4 * HH) {
        float g = bn_g[tid], be = bn_b[tid], m = bn_m[tid], v = bn_v[tid];
        float sc = g * rsqrtf(v + EPS_BN);
        (&s_scale[0][0])[tid] = sc;
        (&s_shift[0][0])[tid] = be - m * sc;
    }
    __syncthreads();

    size_t p = (size_t)blockIdx.x * 256 + tid;
    float2 xv = ((const float2*)x)[p];
    float a[HH], bbuf[HH];
#pragma unroll
    for (int j = 0; j < HH; ++j) {
        float t = s_w1[2 * j] * xv.x + s_w1[2 * j + 1] * xv.y + s_b1[j];
        t = gelu_exact(t);
        a[j] = t * s_scale[0][j] + s_shift[0][j];
    }
    layer64(a, bbuf, &s_w[0][0], &s_b[0][0], s_scale[1], s_shift[1]);
    layer64(bbuf, a, &s_w[1][0], &s_b[1][0], s_scale[2], s_shift[2]);
    layer64(a, bbuf, &s_w[2][0], &s_b[2][0], s_scale[3], s_shift[3]);

    float4* yo = (float4*)(y + p * (size_t)HH);
#pragma unroll
    for (int j4 = 0; j4 < 16; ++j4)
        yo[j4] = make_float4(bbuf[4 * j4], bbuf[4 * j4 + 1], bbuf[4 * j4 + 2], bbuf[4 * j4 + 3]);
}

// ---------------- LSTM: one block per (dir, b); thread=(u, kq); fused FC emission ----------------
__global__ __launch_bounds__(256) void lstm_kernel(
    const float* __restrict__ y,
    const float* __restrict__ wih_f, const float* __restrict__ whh_f,
    const float* __restrict__ bih_f, const float* __restrict__ bhh_f,
    const float* __restrict__ wih_b, const float* __restrict__ whh_b,
    const float* __restrict__ bih_b, const float* __restrict__ bhh_b,
    const float* __restrict__ fc_w, float* __restrict__ em_ws) {
    int blk = blockIdx.x;
    int dir = blk >> 7;
    int b = blk & 127;
    const float* wih = dir ? wih_b : wih_f;
    const float* whh = dir ? whh_b : whh_f;
    const float* bih = dir ? bih_b : bih_f;
    const float* bhh = dir ? bhh_b : bhh_f;

    int tid = threadIdx.x;
    int u = tid >> 2;
    int kq = tid & 3;
    int wv = tid >> 6;
    int lid = tid & 63;

    float4 wir[4][4], whr[4][4];
#pragma unroll
    for (int g = 0; g < 4; ++g) {
#pragma unroll
        for (int m = 0; m < 4; ++m) {
            wir[g][m] = *(const float4*)(wih + (size_t)(g * HH + u) * HH + kq * 16 + m * 4);
            whr[g][m] = *(const float4*)(whh + (size_t)(g * HH + u) * HH + kq * 16 + m * 4);
        }
    }
    float bias[4];
#pragma unroll
    for (int g = 0; g < 4; ++g) bias[g] = bih[g * HH + u] + bhh[g * HH + u];
    float fcw = (kq < 2) ? fc_w[kq * (2 * HH) + dir * HH + u] : 0.0f;

    __shared__ float xb[2][HH];
    __shared__ float hb[2][HH];
    __shared__ float emw[2][4][2];

    int t0 = dir ? (TT - 1) : 0;
    int dstep = dir ? -1 : 1;
    if (lid < 4) {
        ((float4*)xb[0])[wv * 4 + lid] = ((const float4*)(y + ((size_t)b * TT + t0) * HH))[wv * 4 + lid];
    }
    if (tid < HH) hb[0][tid] = 0.0f;
    __syncthreads();

    float c = 0.0f;
    int cur = 0;
    for (int s = 0; s < TT; ++s) {
        int t = t0 + s * dstep;
        float4 xnext4;
        if (lid < 4 && s + 1 < TT)
            xnext4 = ((const float4*)(y + ((size_t)b * TT + t + dstep) * HH))[wv * 4 + lid];

        float acc0 = 0.f, acc1 = 0.f, acc2 = 0.f, acc3 = 0.f;
        const float4* hb4 = (const float4*)hb[cur];
        const float4* xb4 = (const float4*)xb[cur];
#pragma unroll
        for (int m = 0; m < 4; ++m) {
            float4 hv = hb4[kq * 4 + m];
            float4 xv = xb4[kq * 4 + m];
            acc0 += hv.x * whr[0][m].x + hv.y * whr[0][m].y + hv.z * whr[0][m].z + hv.w * whr[0][m].w;
            acc0 += xv.x * wir[0][m].x + xv.y * wir[0][m].y + xv.z * wir[0][m].z + xv.w * wir[0][m].w;
            acc1 += hv.x * whr[1][m].x + hv.y * whr[1][m].y + hv.z * whr[1][m].z + hv.w * whr[1][m].w;
            acc1 += xv.x * wir[1][m].x + xv.y * wir[1][m].y + xv.z * wir[1][m].z + xv.w * wir[1][m].w;
            acc2 += hv.x * whr[2][m].x + hv.y * whr[2][m].y + hv.z * whr[2][m].z + hv.w * whr[2][m].w;
            acc2 += xv.x * wir[2][m].x + xv.y * wir[2][m].y + xv.z * wir[2][m].z + xv.w * wir[2][m].w;
            acc3 += hv.x * whr[3][m].x + hv.y * whr[3][m].y + hv.z * whr[3][m].z + hv.w * whr[3][m].w;
            acc3 += xv.x * wir[3][m].x + xv.y * wir[3][m].y + xv.z * wir[3][m].z + xv.w * wir[3][m].w;
        }
        acc0 += __shfl_xor(acc0, 1); acc0 += __shfl_xor(acc0, 2);
        acc1 += __shfl_xor(acc1, 1); acc1 += __shfl_xor(acc1, 2);
        acc2 += __shfl_xor(acc2, 1); acc2 += __shfl_xor(acc2, 2);
        acc3 += __shfl_xor(acc3, 1); acc3 += __shfl_xor(acc3, 2);

        float zi = acc0 + bias[0], zf = acc1 + bias[1], zg = acc2 + bias[2], zo = acc3 + bias[3];
        float ig = sigm(zi), fg = sigm(zf), gg = tanh_(zg), og = sigm(zo);
        c = fg * c + ig * gg;
        float h = og * tanh_(c);

        float p = h * fcw;
        p += __shfl_xor(p, 4); p += __shfl_xor(p, 8); p += __shfl_xor(p, 16); p += __shfl_xor(p, 32);
        if ((tid & 63) < 2) emw[s & 1][wv][kq] = p;

        if (s > 0 && tid >= 4 && tid < 6) {
            int cc = tid - 4;
            int pb = (s - 1) & 1;
            float e = emw[pb][0][cc] + emw[pb][1][cc] + emw[pb][2][cc] + emw[pb][3][cc];
            int tp = t - dstep;
            em_ws[(((size_t)dir * TT + tp) * BB + b) * 2 + cc] = e;
        }

        if (kq == 0) hb[cur ^ 1][u] = h;
        if (lid < 4 && s + 1 < TT) ((float4*)xb[cur ^ 1])[wv * 4 + lid] = xnext4;
        __syncthreads();
        cur ^= 1;
    }
    if (tid >= 4 && tid < 6) {
        int cc = tid - 4;
        int pb = (TT - 1) & 1;
        float e = emw[pb][0][cc] + emw[pb][1][cc] + emw[pb][2][cc] + emw[pb][3][cc];
        int tl = t0 + (TT - 1) * dstep;
        em_ws[(((size_t)dir * TT + tl) * BB + b) * 2 + cc] = e;
    }
}

// ---------------- CRF: forward algorithm + gold score, thread = batch element ----------------
__global__ __launch_bounds__(128) void crf_kernel(
    const float* __restrict__ em_ws, const int* __restrict__ tags,
    const float* __restrict__ fc_b, const float* __restrict__ crf_start,
    const float* __restrict__ crf_end, const float* __restrict__ crf_trans,
    float* __restrict__ out) {
    int b = threadIdx.x;
    float fb0 = fc_b[0], fb1 = fc_b[1];
    float t00 = crf_trans[0], t01 = crf_trans[1], t10 = crf_trans[2], t11 = crf_trans[3];
    float s0 = crf_start[0], s1 = crf_start[1];
    float ee0 = crf_end[0], ee1 = crf_end[1];
    const float2* p0 = (const float2*)em_ws;       // [(t)*B + b]
    const float2* p1 = p0 + (size_t)TT * BB;       // dir 1
    const int* tgp = tags + (size_t)b * TT;

    float2 ea = p0[b];
    float2 eb = p1[b];
    float e0 = ea.x + eb.x + fb0;
    float e1 = ea.y + eb.y + fb1;
    float a0 = s0 + e0, a1 = s1 + e1;
    int tp = tgp[0];
    float num = (tp ? s1 : s0) + (tp ? e1 : e0);

    int t = 1;
    for (; t + 8 <= TT; t += 8) {
        float2 ca[8], cb[8];
        int ct[8];
#pragma unroll
        for (int i = 0; i < 8; ++i) {
            ca[i] = p0[(size_t)(t + i) * BB + b];
            cb[i] = p1[(size_t)(t + i) * BB + b];
            ct[i] = tgp[t + i];
        }
#pragma unroll
        for (int i = 0; i < 8; ++i) {
            float f0 = ca[i].x + cb[i].x + fb0;
            float f1 = ca[i].y + cb[i].y + fb1;
            float n0 = lse2(a0 + t00, a1 + t10) + f0;
            float n1 = lse2(a0 + t01, a1 + t11) + f1;
            a0 = n0; a1 = n1;
            int tgi = ct[i];
            num += (tgi ? f1 : f0) + (tp ? (tgi ? t11 : t10) : (tgi ? t01 : t00));
            tp = tgi;
        }
    }
    for (; t < TT; ++t) {
        float2 ca = p0[(size_t)t * BB + b];
        float2 cb = p1[(size_t)t * BB + b];
        float f0 = ca.x + cb.x + fb0;
        float f1 = ca.y + cb.y + fb1;
        float n0 = lse2(a0 + t00, a1 + t10) + f0;
        float n1 = lse2(a0 + t01, a1 + t11) + f1;
        a0 = n0; a1 = n1;
        int tgi = tgp[t];
        num += (tgi ? f1 : f0) + (tp ? (tgi ? t11 : t10) : (tgi ? t01 : t00));
        tp = tgi;
    }
    num += tp ? ee1 : ee0;
    float logZ = lse2(a0 + ee0, a1 + ee1);
    float nll = logZ - num;
    __shared__ float red[BB];
    red[b] = nll;
    __syncthreads();
    if (b == 0) {
        float s = 0.f;
        for (int i = 0; i < BB; ++i) s += red[i];
        out[0] = s;
    }
}

extern "C" void kernel_launch(void* const* d_in, const int* in_sizes, int n_in,
                              void* d_out, int out_size, void* d_ws, size_t ws_size,
                              hipStream_t stream) {
    const float* x = (const float*)d_in[0];
    const int* tags = (const int*)d_in[1];
    const float* cw1 = (const float*)d_in[2];
    const float* cb1 = (const float*)d_in[3];
    const float* cwr = (const float*)d_in[4];
    const float* cbr = (const float*)d_in[5];
    const float* bn_g = (const float*)d_in[6];
    const float* bn_b = (const float*)d_in[7];
    const float* bn_m = (const float*)d_in[8];
    const float* bn_v = (const float*)d_in[9];
    const float* wih_f = (const float*)d_in[10];
    const float* whh_f = (const float*)d_in[11];
    const float* bih_f = (const float*)d_in[12];
    const float* bhh_f = (const float*)d_in[13];
    const float* wih_b = (const float*)d_in[14];
    const float* whh_b = (const float*)d_in[15];
    const float* bih_b = (const float*)d_in[16];
    const float* bhh_b = (const float*)d_in[17];
    const float* fc_w = (const float*)d_in[18];
    const float* fc_b = (const float*)d_in[19];
    const float* crf_start = (const float*)d_in[20];
    const float* crf_end = (const float*)d_in[21];
    const float* crf_trans = (const float*)d_in[22];
    float* out = (float*)d_out;

    float* y = (float*)d_ws;                          // [B*T*64] f32 = 64 MB
    float* em = y + (size_t)BB * TT * HH;             // [2*T*B*2] f32 = 4 MB

    conv_kernel<<<(BB * TT) / 256, 256, 0, stream>>>(x, cw1, cb1, cwr, cbr, bn_g, bn_b, bn_m, bn_v, y);
    lstm_kernel<<<256, 256, 0, stream>>>(y, wih_f, whh_f, bih_f, bhh_f,
                                         wih_b, whh_b, bih_b, bhh_b, fc_w, em);
    crf_kernel<<<1, 128, 0, stream>>>(em, tags, fc_b, crf_start, crf_end, crf_trans, out);
}

// Round 5
// 2231.772 us; speedup vs baseline: 1.8298x; 1.8298x over previous
//
#include <hip/hip_runtime.h>
#include <hip/hip_bf16.h>

#define BB 128
#define TT 2048
#define HH 64
#define BT (BB * TT)
#define EPS_BN 1e-5f

typedef unsigned short ushort_t;
typedef short s8v __attribute__((ext_vector_type(8)));   // 8 bf16 as shorts (4 VGPRs)
typedef float f4v __attribute__((ext_vector_type(4)));   // MFMA accum

__device__ __forceinline__ float gelu_exact(float x) {
    return 0.5f * x * (1.0f + erff(x * 0.70710678118654752440f));
}
__device__ __forceinline__ ushort_t f2bf(float v) {
    __hip_bfloat16 h = __float2bfloat16(v);
    return *reinterpret_cast<ushort_t*>(&h);
}
__device__ __forceinline__ float lse2(float a, float b) {
    float m = fmaxf(a, b);
    return m + log1pf(__expf(-fabsf(a - b)));
}

// ================= Kernel A: conv stack (MFMA bf16) -> y bf16 [B*T][64] =================
__global__ __launch_bounds__(256, 4) void conv_kernel(
    const float* __restrict__ x, const float* __restrict__ cw1, const float* __restrict__ cb1,
    const float* __restrict__ cwr, const float* __restrict__ cbr,
    const float* __restrict__ bn_g, const float* __restrict__ bn_b,
    const float* __restrict__ bn_m, const float* __restrict__ bn_v,
    ushort_t* __restrict__ y) {
    __shared__ ushort_t s_wc[3 * 64 * 64];   // swizzled bf16 conv weights (24 KB)
    __shared__ float s_l1[64 * 4];
    __shared__ float s_sc[256], s_sh[256];
    __shared__ float s_cb[192];
    __shared__ ushort_t s_act[4][1024];      // per-wave 16x64 bf16 act (8 KB)

    int tid = threadIdx.x;
    for (int i = tid; i < 3 * 64 * 64; i += 256) {
        int row = (i >> 6) & 63, col = i & 63;
        unsigned by = (unsigned)((i >> 6) * 128 + col * 2) ^ (unsigned)((row & 7) << 4);
        s_wc[by >> 1] = f2bf(cwr[i]);
    }
    if (tid < 64) {
        s_l1[tid * 4 + 0] = cw1[tid * 2 + 0];
        s_l1[tid * 4 + 1] = cw1[tid * 2 + 1];
        s_l1[tid * 4 + 2] = cb1[tid];
    }
    if (tid < 256) {
        float sc = bn_g[tid] * rsqrtf(bn_v[tid] + EPS_BN);
        s_sc[tid] = sc;
        s_sh[tid] = bn_b[tid] - bn_m[tid] * sc;
    }
    if (tid < 192) s_cb[tid] = cbr[tid];
    __syncthreads();

    int wid = tid >> 6, l = tid & 63;
    int lrow = l & 15, lgrp = l >> 4;
    ushort_t* act = s_act[wid];
    int gwave = blockIdx.x * 4 + wid;        // 1024 blocks * 4 waves = 4096

    for (int strip = gwave; strip < 16384; strip += 4096) {
        int p0 = strip << 4;
        float2 xv = ((const float2*)x)[p0 + lrow];
        s8v fa0, fa1;
#pragma unroll
        for (int j = 0; j < 8; ++j) {
            int c0 = lgrp * 8 + j, c1 = 32 + c0;
            float t0 = s_l1[c0 * 4] * xv.x + s_l1[c0 * 4 + 1] * xv.y + s_l1[c0 * 4 + 2];
            t0 = gelu_exact(t0) * s_sc[c0] + s_sh[c0];
            fa0[j] = (short)f2bf(t0);
            float t1 = s_l1[c1 * 4] * xv.x + s_l1[c1 * 4 + 1] * xv.y + s_l1[c1 * 4 + 2];
            t1 = gelu_exact(t1) * s_sc[c1] + s_sh[c1];
            fa1[j] = (short)f2bf(t1);
        }
#pragma unroll
        for (int L = 0; L < 3; ++L) {
            f4v acc[4];
#pragma unroll
            for (int nt = 0; nt < 4; ++nt) {
                acc[nt] = (f4v){0.f, 0.f, 0.f, 0.f};
                int row = nt * 16 + lrow;
                unsigned b0 = (unsigned)(L * 8192 + row * 128 + lgrp * 16) ^ (unsigned)((row & 7) << 4);
                unsigned b1 = (unsigned)(L * 8192 + row * 128 + lgrp * 16 + 64) ^ (unsigned)((row & 7) << 4);
                s8v fb0 = *(const s8v*)((const char*)s_wc + b0);
                s8v fb1 = *(const s8v*)((const char*)s_wc + b1);
                acc[nt] = __builtin_amdgcn_mfma_f32_16x16x32_bf16(fa0, fb0, acc[nt], 0, 0, 0);
                acc[nt] = __builtin_amdgcn_mfma_f32_16x16x32_bf16(fa1, fb1, acc[nt], 0, 0, 0);
            }
#pragma unroll
            for (int nt = 0; nt < 4; ++nt) {
                int ch = nt * 16 + lrow;
#pragma unroll
                for (int i = 0; i < 4; ++i) {
                    float v = acc[nt][i] + s_cb[L * 64 + ch];
                    v = gelu_exact(v) * s_sc[(L + 1) * 64 + ch] + s_sh[(L + 1) * 64 + ch];
                    int pos = lgrp * 4 + i;
                    unsigned by = (unsigned)(pos * 128 + ch * 2) ^ (unsigned)((pos & 7) << 4);
                    *(ushort_t*)((char*)act + by) = f2bf(v);
                }
            }
            if (L < 2) {
                unsigned r0 = (unsigned)(lrow * 128 + lgrp * 16) ^ (unsigned)((lrow & 7) << 4);
                unsigned r1 = (unsigned)(lrow * 128 + lgrp * 16 + 64) ^ (unsigned)((lrow & 7) << 4);
                fa0 = *(const s8v*)((const char*)act + r0);
                fa1 = *(const s8v*)((const char*)act + r1);
            }
        }
        // final: 32B per lane -> y (coalesced 2KB per wave)
        int prow = l >> 2, pc = l & 3;
        unsigned so0 = (unsigned)(prow * 128 + pc * 32) ^ (unsigned)((prow & 7) << 4);
        unsigned so1 = (unsigned)(prow * 128 + pc * 32 + 16) ^ (unsigned)((prow & 7) << 4);
        s8v v0 = *(const s8v*)((const char*)act + so0);
        s8v v1 = *(const s8v*)((const char*)act + so1);
        char* yb = (char*)y + (size_t)(p0 + prow) * 128 + pc * 32;
        *(s8v*)yb = v0;
        *(s8v*)(yb + 16) = v1;
    }
}

// ================= Kernel B: BiLSTM, block=(dir,b); per-16-step MFMA projection =================
__device__ __forceinline__ void em_emit(const float (*hist)[64], s8v femB0, s8v femB1,
                                        int lrow, int lgrp, float* __restrict__ em_ws,
                                        int dir, int b, int t_base, int dstep) {
    s8v fa0, fa1;
#pragma unroll
    for (int jj = 0; jj < 8; ++jj) {
        fa0[jj] = (short)f2bf(hist[lrow][lgrp * 8 + jj]);
        fa1[jj] = (short)f2bf(hist[lrow][32 + lgrp * 8 + jj]);
    }
    f4v acc = (f4v){0.f, 0.f, 0.f, 0.f};
    acc = __builtin_amdgcn_mfma_f32_16x16x32_bf16(fa0, femB0, acc, 0, 0, 0);
    acc = __builtin_amdgcn_mfma_f32_16x16x32_bf16(fa1, femB1, acc, 0, 0, 0);
    if (lrow < 2) {
#pragma unroll
        for (int i = 0; i < 4; ++i) {
            int s_loc = lgrp * 4 + i;
            int t = t_base + dstep * s_loc;
            em_ws[(((size_t)dir * TT + t) * BB + b) * 2 + lrow] = acc[i];
        }
    }
}

#define DOT4(g) (h0.x*wq[g][0].x + h0.y*wq[g][0].y + h0.z*wq[g][0].z + h0.w*wq[g][0].w \
               + h1.x*wq[g][1].x + h1.y*wq[g][1].y + h1.z*wq[g][1].z + h1.w*wq[g][1].w \
               + h2.x*wq[g][2].x + h2.y*wq[g][2].y + h2.z*wq[g][2].z + h2.w*wq[g][2].w \
               + h3.x*wq[g][3].x + h3.y*wq[g][3].y + h3.z*wq[g][3].z + h3.w*wq[g][3].w)

__global__ __launch_bounds__(256, 1) void lstm_kernel(
    const ushort_t* __restrict__ y,
    const float* __restrict__ whh_f, const float* __restrict__ whh_b,
    const float* __restrict__ wih_f, const float* __restrict__ wih_b,
    const float* __restrict__ bih_f, const float* __restrict__ bhh_f,
    const float* __restrict__ bih_b, const float* __restrict__ bhh_b,
    const float* __restrict__ fc_w, float* __restrict__ em_ws) {
    int blk = blockIdx.x;
    int dir = blk >> 7;
    int b = blk & 127;
    const float* whh = dir ? whh_b : whh_f;
    const float* wih = dir ? wih_b : wih_f;
    const float* bih = dir ? bih_b : bih_f;
    const float* bhh = dir ? bhh_b : bhh_f;

    int tid = threadIdx.x;
    int u = tid >> 2, kq = tid & 3;
    int wid = tid >> 6, l = tid & 63;
    int lrow = l & 15, lgrp = l >> 4;

    __shared__ ushort_t s_wih[256 * 64];    // 32 KB, XOR-swizzled
    __shared__ float s_pb[256];
    __shared__ float zbuf[16][256];         // 16 KB
    __shared__ ushort_t s_y[16 * 64];       // 2 KB, XOR-swizzled
    __shared__ float hist[16][64];          // 4 KB

    for (int i = tid; i < 256 * 64; i += 256) {
        int row = i >> 6, col = i & 63;
        unsigned by = (unsigned)(row * 128 + col * 2) ^ (unsigned)((row & 7) << 4);
        s_wih[by >> 1] = f2bf(wih[i]);
    }
    s_pb[tid] = bih[tid] + bhh[tid];
    if (tid < 64) hist[15][tid] = 0.f;

    float4 wq[4][4];
#pragma unroll
    for (int g = 0; g < 4; ++g)
#pragma unroll
        for (int m = 0; m < 4; ++m)
            wq[g][m] = *(const float4*)(whh + (size_t)(g * 64 + u) * 64 + kq * 16 + m * 4);

    s8v femB0 = {0, 0, 0, 0, 0, 0, 0, 0}, femB1 = {0, 0, 0, 0, 0, 0, 0, 0};
    if (wid == 0 && lrow < 2) {
#pragma unroll
        for (int jj = 0; jj < 8; ++jj) {
            int u0 = lgrp * 8 + jj;
            femB0[jj] = (short)f2bf(fc_w[lrow * 128 + dir * 64 + u0]);
            femB1[jj] = (short)f2bf(fc_w[lrow * 128 + dir * 64 + 32 + u0]);
        }
    }

    int t0 = dir ? (TT - 1) : 0;
    int dstep = dir ? -1 : 1;
    int m_st = tid >> 4, ch4 = tid & 15;
    const char* ybase = (const char*)y + (size_t)b * TT * 128;
    unsigned sy_by = (unsigned)(m_st * 128 + ch4 * 8) ^ (unsigned)((m_st & 7) << 4);
    uint2 yreg = *(const uint2*)(ybase + (size_t)(t0 + dstep * m_st) * 128 + ch4 * 8);

    __syncthreads();

    float c = 0.f;
    for (int strip = 0; strip < 128; ++strip) {
        // ---- stage y tile ----
        *(uint2*)((char*)s_y + sy_by) = yreg;
        __syncthreads();
        // ---- projection MFMA phase (+ emission GEMM for previous strip, wave 0) ----
        {
            s8v fa0 = *(const s8v*)((const char*)s_y +
                        ((unsigned)(lrow * 128 + lgrp * 16) ^ (unsigned)((lrow & 7) << 4)));
            s8v fa1 = *(const s8v*)((const char*)s_y +
                        ((unsigned)(lrow * 128 + lgrp * 16 + 64) ^ (unsigned)((lrow & 7) << 4)));
#pragma unroll
            for (int nt = 0; nt < 4; ++nt) {
                int row = wid * 64 + nt * 16 + lrow;
                s8v fb0 = *(const s8v*)((const char*)s_wih +
                            ((unsigned)(row * 128 + lgrp * 16) ^ (unsigned)((row & 7) << 4)));
                s8v fb1 = *(const s8v*)((const char*)s_wih +
                            ((unsigned)(row * 128 + lgrp * 16 + 64) ^ (unsigned)((row & 7) << 4)));
                f4v acc = (f4v){0.f, 0.f, 0.f, 0.f};
                acc = __builtin_amdgcn_mfma_f32_16x16x32_bf16(fa0, fb0, acc, 0, 0, 0);
                acc = __builtin_amdgcn_mfma_f32_16x16x32_bf16(fa1, fb1, acc, 0, 0, 0);
                int u_ = nt * 16 + lrow;          // row & 63 ; gate = wid
                float bias = s_pb[row];
#pragma unroll
                for (int i = 0; i < 4; ++i) {
                    int pos = lgrp * 4 + i;
                    zbuf[pos][(u_ * 4 + wid) ^ lgrp] = acc[i] + bias;
                }
            }
            if (strip > 0 && wid == 0)
                em_emit(hist, femB0, femB1, lrow, lgrp, em_ws, dir, b,
                        t0 + dstep * ((strip - 1) * 16), dstep);
        }
        __syncthreads();
        // ---- preload this strip's z into registers ----
        float z_reg[16];
#pragma unroll
        for (int j = 0; j < 16; ++j) z_reg[j] = zbuf[j][tid ^ ((j >> 2) & 3)];
        // ---- prefetch next tile (consumed 16 steps later) ----
        if (strip + 1 < 128) {
            int tn = t0 + dstep * ((strip + 1) * 16 + m_st);
            yreg = *(const uint2*)(ybase + (size_t)tn * 128 + ch4 * 8);
        }
        // ---- 16 recurrent steps ----
#pragma unroll
        for (int j = 0; j < 16; ++j) {
            int jm1 = (j + 15) & 15;
            const float4* hb4 = (const float4*)&hist[jm1][kq * 16];
            float4 h0 = hb4[0], h1 = hb4[1], h2 = hb4[2], h3 = hb4[3];
            float a0 = DOT4(0), a1 = DOT4(1), a2 = DOT4(2), a3 = DOT4(3);
            float zr = z_reg[j];
            a0 += (kq == 0) ? zr : 0.f;
            a1 += (kq == 1) ? zr : 0.f;
            a2 += (kq == 2) ? zr : 0.f;
            a3 += (kq == 3) ? zr : 0.f;
            a0 += __shfl_xor(a0, 1); a0 += __shfl_xor(a0, 2);
            a1 += __shfl_xor(a1, 1); a1 += __shfl_xor(a1, 2);
            a2 += __shfl_xor(a2, 1); a2 += __shfl_xor(a2, 2);
            a3 += __shfl_xor(a3, 1); a3 += __shfl_xor(a3, 2);
            float zg = (kq == 0) ? a0 : (kq == 1) ? a1 : (kq == 2) ? a2 : a3;
            float sgm = 1.f / (1.f + __expf((kq == 2) ? (-zg - zg) : -zg));
            float val = (kq == 2) ? (2.f * sgm - 1.f) : sgm;
            float v1 = __shfl_xor(val, 1), v2 = __shfl_xor(val, 2), v3 = __shfl_xor(val, 3);
            float gi = (kq == 0) ? val : (kq == 1) ? v1 : (kq == 2) ? v2 : v3;
            float gf = (kq == 1) ? val : (kq == 0) ? v1 : (kq == 3) ? v2 : v3;
            float gg = (kq == 2) ? val : (kq == 3) ? v1 : (kq == 0) ? v2 : v3;
            float go = (kq == 3) ? val : (kq == 2) ? v1 : (kq == 1) ? v2 : v3;
            c = gf * c + gi * gg;
            float e2 = __expf(2.f * c);
            float h = go * (1.f - 2.f / (e2 + 1.f));
            if (kq == 0) hist[j][u] = h;
            __syncthreads();
        }
    }
    // emission GEMM for the last strip
    if (wid == 0)
        em_emit(hist, femB0, femB1, lrow, lgrp, em_ws, dir, b,
                t0 + dstep * (127 * 16), dstep);
}

// ================= Kernel C: CRF forward + gold score =================
__global__ __launch_bounds__(128) void crf_kernel(
    const float* __restrict__ em_ws, const int* __restrict__ tags,
    const float* __restrict__ fc_b, const float* __restrict__ crf_start,
    const float* __restrict__ crf_end, const float* __restrict__ crf_trans,
    float* __restrict__ out) {
    int b = threadIdx.x;
    float fb0 = fc_b[0], fb1 = fc_b[1];
    float t00 = crf_trans[0], t01 = crf_trans[1], t10 = crf_trans[2], t11 = crf_trans[3];
    float s0 = crf_start[0], s1 = crf_start[1];
    float ee0 = crf_end[0], ee1 = crf_end[1];
    const float2* p0 = (const float2*)em_ws;
    const float2* p1 = p0 + (size_t)TT * BB;
    const int* tgp = tags + (size_t)b * TT;

    float2 ea = p0[b];
    float2 eb = p1[b];
    float e0 = ea.x + eb.x + fb0;
    float e1 = ea.y + eb.y + fb1;
    float a0 = s0 + e0, a1 = s1 + e1;
    int tp = tgp[0];
    float num = (tp ? s1 : s0) + (tp ? e1 : e0);

    int t = 1;
    for (; t + 8 <= TT; t += 8) {
        float2 ca[8], cb[8];
        int ct[8];
#pragma unroll
        for (int i = 0; i < 8; ++i) {
            ca[i] = p0[(size_t)(t + i) * BB + b];
            cb[i] = p1[(size_t)(t + i) * BB + b];
            ct[i] = tgp[t + i];
        }
#pragma unroll
        for (int i = 0; i < 8; ++i) {
            float f0 = ca[i].x + cb[i].x + fb0;
            float f1 = ca[i].y + cb[i].y + fb1;
            float n0 = lse2(a0 + t00, a1 + t10) + f0;
            float n1 = lse2(a0 + t01, a1 + t11) + f1;
            a0 = n0; a1 = n1;
            int tgi = ct[i];
            num += (tgi ? f1 : f0) + (tp ? (tgi ? t11 : t10) : (tgi ? t01 : t00));
            tp = tgi;
        }
    }
    for (; t < TT; ++t) {
        float2 ca = p0[(size_t)t * BB + b];
        float2 cb = p1[(size_t)t * BB + b];
        float f0 = ca.x + cb.x + fb0;
        float f1 = ca.y + cb.y + fb1;
        float n0 = lse2(a0 + t00, a1 + t10) + f0;
        float n1 = lse2(a0 + t01, a1 + t11) + f1;
        a0 = n0; a1 = n1;
        int tgi = tgp[t];
        num += (tgi ? f1 : f0) + (tp ? (tgi ? t11 : t10) : (tgi ? t01 : t00));
        tp = tgi;
    }
    num += tp ? ee1 : ee0;
    float logZ = lse2(a0 + ee0, a1 + ee1);
    float nll = logZ - num;
    __shared__ float red[BB];
    red[b] = nll;
    __syncthreads();
    if (b == 0) {
        float s = 0.f;
        for (int i = 0; i < BB; ++i) s += red[i];
        out[0] = s;
    }
}

extern "C" void kernel_launch(void* const* d_in, const int* in_sizes, int n_in,
                              void* d_out, int out_size, void* d_ws, size_t ws_size,
                              hipStream_t stream) {
    const float* x = (const float*)d_in[0];
    const int* tags = (const int*)d_in[1];
    const float* cw1 = (const float*)d_in[2];
    const float* cb1 = (const float*)d_in[3];
    const float* cwr = (const float*)d_in[4];
    const float* cbr = (const float*)d_in[5];
    const float* bn_g = (const float*)d_in[6];
    const float* bn_b = (const float*)d_in[7];
    const float* bn_m = (const float*)d_in[8];
    const float* bn_v = (const float*)d_in[9];
    const float* wih_f = (const float*)d_in[10];
    const float* whh_f = (const float*)d_in[11];
    const float* bih_f = (const float*)d_in[12];
    const float* bhh_f = (const float*)d_in[13];
    const float* wih_b = (const float*)d_in[14];
    const float* whh_b = (const float*)d_in[15];
    const float* bih_b = (const float*)d_in[16];
    const float* bhh_b = (const float*)d_in[17];
    const float* fc_w = (const float*)d_in[18];
    const float* fc_b = (const float*)d_in[19];
    const float* crf_start = (const float*)d_in[20];
    const float* crf_end = (const float*)d_in[21];
    const float* crf_trans = (const float*)d_in[22];
    float* out = (float*)d_out;

    ushort_t* y = (ushort_t*)d_ws;                                   // B*T*64 bf16 = 32 MiB
    float* em = (float*)((char*)d_ws + (size_t)BT * 64 * 2);         // 2*T*B*2 f32 = 4 MiB

    conv_kernel<<<1024, 256, 0, stream>>>(x, cw1, cb1, cwr, cbr, bn_g, bn_b, bn_m, bn_v, y);
    lstm_kernel<<<256, 256, 0, stream>>>(y, whh_f, whh_b, wih_f, wih_b,
                                         bih_f, bhh_f, bih_b, bhh_b, fc_w, em);
    crf_kernel<<<1, 128, 0, stream>>>(em, tags, fc_b, crf_start, crf_end, crf_trans, out);
}

// Round 6
// 2199.262 us; speedup vs baseline: 1.8568x; 1.0148x over previous
//
#include <hip/hip_runtime.h>
#include <hip/hip_bf16.h>

#define BB 128
#define TT 2048
#define HH 64
#define BT (BB * TT)
#define EPS_BN 1e-5f

typedef unsigned short ushort_t;
typedef short s8v __attribute__((ext_vector_type(8)));   // 8 bf16 as shorts (4 VGPRs)
typedef float f4v __attribute__((ext_vector_type(4)));   // MFMA accum

__device__ __forceinline__ float gelu_exact(float x) {
    return 0.5f * x * (1.0f + erff(x * 0.70710678118654752440f));
}
__device__ __forceinline__ ushort_t f2bf(float v) {
    __hip_bfloat16 h = __float2bfloat16(v);
    return *reinterpret_cast<ushort_t*>(&h);
}
__device__ __forceinline__ float lse2(float a, float b) {
    float m = fmaxf(a, b);
    return m + log1pf(__expf(-fabsf(a - b)));
}

// ================= Kernel A: conv stack (MFMA bf16) -> y bf16 [B*T][64] =================
__global__ __launch_bounds__(256, 4) void conv_kernel(
    const float* __restrict__ x, const float* __restrict__ cw1, const float* __restrict__ cb1,
    const float* __restrict__ cwr, const float* __restrict__ cbr,
    const float* __restrict__ bn_g, const float* __restrict__ bn_b,
    const float* __restrict__ bn_m, const float* __restrict__ bn_v,
    ushort_t* __restrict__ y) {
    __shared__ ushort_t s_wc[3 * 64 * 64];   // swizzled bf16 conv weights (24 KB)
    __shared__ float s_l1[64 * 4];
    __shared__ float s_sc[256], s_sh[256];
    __shared__ float s_cb[192];
    __shared__ ushort_t s_act[4][1024];      // per-wave 16x64 bf16 act (8 KB)

    int tid = threadIdx.x;
    for (int i = tid; i < 3 * 64 * 64; i += 256) {
        int row = (i >> 6) & 63, col = i & 63;
        unsigned by = (unsigned)((i >> 6) * 128 + col * 2) ^ (unsigned)((row & 7) << 4);
        s_wc[by >> 1] = f2bf(cwr[i]);
    }
    if (tid < 64) {
        s_l1[tid * 4 + 0] = cw1[tid * 2 + 0];
        s_l1[tid * 4 + 1] = cw1[tid * 2 + 1];
        s_l1[tid * 4 + 2] = cb1[tid];
    }
    if (tid < 256) {
        float sc = bn_g[tid] * rsqrtf(bn_v[tid] + EPS_BN);
        s_sc[tid] = sc;
        s_sh[tid] = bn_b[tid] - bn_m[tid] * sc;
    }
    if (tid < 192) s_cb[tid] = cbr[tid];
    __syncthreads();

    int wid = tid >> 6, l = tid & 63;
    int lrow = l & 15, lgrp = l >> 4;
    ushort_t* act = s_act[wid];
    int gwave = blockIdx.x * 4 + wid;        // 1024 blocks * 4 waves = 4096

    for (int strip = gwave; strip < 16384; strip += 4096) {
        int p0 = strip << 4;
        float2 xv = ((const float2*)x)[p0 + lrow];
        s8v fa0, fa1;
#pragma unroll
        for (int j = 0; j < 8; ++j) {
            int c0 = lgrp * 8 + j, c1 = 32 + c0;
            float t0 = s_l1[c0 * 4] * xv.x + s_l1[c0 * 4 + 1] * xv.y + s_l1[c0 * 4 + 2];
            t0 = gelu_exact(t0) * s_sc[c0] + s_sh[c0];
            fa0[j] = (short)f2bf(t0);
            float t1 = s_l1[c1 * 4] * xv.x + s_l1[c1 * 4 + 1] * xv.y + s_l1[c1 * 4 + 2];
            t1 = gelu_exact(t1) * s_sc[c1] + s_sh[c1];
            fa1[j] = (short)f2bf(t1);
        }
#pragma unroll
        for (int L = 0; L < 3; ++L) {
            f4v acc[4];
#pragma unroll
            for (int nt = 0; nt < 4; ++nt) {
                acc[nt] = (f4v){0.f, 0.f, 0.f, 0.f};
                int row = nt * 16 + lrow;
                unsigned b0 = (unsigned)(L * 8192 + row * 128 + lgrp * 16) ^ (unsigned)((row & 7) << 4);
                unsigned b1 = (unsigned)(L * 8192 + row * 128 + lgrp * 16 + 64) ^ (unsigned)((row & 7) << 4);
                s8v fb0 = *(const s8v*)((const char*)s_wc + b0);
                s8v fb1 = *(const s8v*)((const char*)s_wc + b1);
                acc[nt] = __builtin_amdgcn_mfma_f32_16x16x32_bf16(fa0, fb0, acc[nt], 0, 0, 0);
                acc[nt] = __builtin_amdgcn_mfma_f32_16x16x32_bf16(fa1, fb1, acc[nt], 0, 0, 0);
            }
#pragma unroll
            for (int nt = 0; nt < 4; ++nt) {
                int ch = nt * 16 + lrow;
#pragma unroll
                for (int i = 0; i < 4; ++i) {
                    float v = acc[nt][i] + s_cb[L * 64 + ch];
                    v = gelu_exact(v) * s_sc[(L + 1) * 64 + ch] + s_sh[(L + 1) * 64 + ch];
                    int pos = lgrp * 4 + i;
                    unsigned by = (unsigned)(pos * 128 + ch * 2) ^ (unsigned)((pos & 7) << 4);
                    *(ushort_t*)((char*)act + by) = f2bf(v);
                }
            }
            if (L < 2) {
                unsigned r0 = (unsigned)(lrow * 128 + lgrp * 16) ^ (unsigned)((lrow & 7) << 4);
                unsigned r1 = (unsigned)(lrow * 128 + lgrp * 16 + 64) ^ (unsigned)((lrow & 7) << 4);
                fa0 = *(const s8v*)((const char*)act + r0);
                fa1 = *(const s8v*)((const char*)act + r1);
            }
        }
        int prow = l >> 2, pc = l & 3;
        unsigned so0 = (unsigned)(prow * 128 + pc * 32) ^ (unsigned)((prow & 7) << 4);
        unsigned so1 = (unsigned)(prow * 128 + pc * 32 + 16) ^ (unsigned)((prow & 7) << 4);
        s8v v0 = *(const s8v*)((const char*)act + so0);
        s8v v1 = *(const s8v*)((const char*)act + so1);
        char* yb = (char*)y + (size_t)(p0 + prow) * 128 + pc * 32;
        *(s8v*)yb = v0;
        *(s8v*)(yb + 16) = v1;
    }
}

// ================= Kernel B: BiLSTM via MFMA recurrence, block=(dir, 16 batches) =================
// h ring: 8 slots of [16b][64u] bf16, XOR-swizzled: byte = slot*2048 + ((b*128 + u*2) ^ ((b&7)<<4))
__device__ __forceinline__ unsigned ring_addr(int slot, int bb, int ub) {
    return (unsigned)(slot * 2048) + (((unsigned)(bb * 128 + ub)) ^ ((unsigned)((bb & 7) << 4)));
}

template <int PAR>
__device__ __forceinline__ void lstm_strip(
    int s, int w, int lb, int lg, int b, int d, int t0, int dstep,
    const s8v (&whhA)[4][2], const s8v (&wihA)[4][2],
    const f4v (&zbias)[4], const s8v (&femA)[2],
    const s8v (&ybCur)[4][2], s8v (&ybNxt)[4][2],
    float (&cst)[4], ushort_t* ring,
    const char* __restrict__ ybase, float2* __restrict__ emv) {
    // ---- input-projection for this strip's 4 timesteps (zin stays in registers) ----
    f4v zin[4][4];
#pragma unroll
    for (int g = 0; g < 4; ++g)
#pragma unroll
        for (int ct = 0; ct < 4; ++ct) {
            f4v a = zbias[g];
            a = __builtin_amdgcn_mfma_f32_16x16x32_bf16(wihA[g][0], ybCur[ct][0], a, 0, 0, 0);
            a = __builtin_amdgcn_mfma_f32_16x16x32_bf16(wihA[g][1], ybCur[ct][1], a, 0, 0, 0);
            zin[g][ct] = a;
        }
    // ---- prefetch next strip's y B-fragments straight from global ----
    if (s + 1 < 512) {
#pragma unroll
        for (int ct = 0; ct < 4; ++ct) {
            int t = t0 + dstep * ((s + 1) * 4 + ct);
            const char* p = ybase + (size_t)t * 128 + lg * 16;
            ybNxt[ct][0] = *(const s8v*)p;
            ybNxt[ct][1] = *(const s8v*)(p + 64);
        }
    }
    // ---- emissions for previous strip (wave 0 only; reads the other ring half) ----
    if (w == 0 && s > 0) {
#pragma unroll
        for (int ct = 0; ct < 4; ++ct) {
            int slot = (1 - PAR) * 4 + ct;
            s8v hlo = *(const s8v*)((const char*)ring + ring_addr(slot, lb, lg * 16));
            s8v hhi = *(const s8v*)((const char*)ring + ring_addr(slot, lb, 64 + lg * 16));
            f4v a = (f4v){0.f, 0.f, 0.f, 0.f};
            a = __builtin_amdgcn_mfma_f32_16x16x32_bf16(femA[0], hlo, a, 0, 0, 0);
            a = __builtin_amdgcn_mfma_f32_16x16x32_bf16(femA[1], hhi, a, 0, 0, 0);
            if (lg == 0) {
                int t = t0 + dstep * ((s - 1) * 4 + ct);
                emv[((size_t)d * TT + t) * BB + b] = make_float2(a[0], a[1]);
            }
        }
    }
    // ---- 4 recurrent steps, one barrier each ----
#pragma unroll
    for (int j = 0; j < 4; ++j) {
        const int prev = (j == 0) ? ((1 - PAR) * 4 + 3) : (PAR * 4 + j - 1);
        const int slot = PAR * 4 + j;
        s8v hlo = *(const s8v*)((const char*)ring + ring_addr(prev, lb, lg * 16));
        s8v hhi = *(const s8v*)((const char*)ring + ring_addr(prev, lb, 64 + lg * 16));
        f4v a0 = __builtin_amdgcn_mfma_f32_16x16x32_bf16(whhA[0][0], hlo, zin[0][j], 0, 0, 0);
        f4v a1 = __builtin_amdgcn_mfma_f32_16x16x32_bf16(whhA[1][0], hlo, zin[1][j], 0, 0, 0);
        f4v a2 = __builtin_amdgcn_mfma_f32_16x16x32_bf16(whhA[2][0], hlo, zin[2][j], 0, 0, 0);
        f4v a3 = __builtin_amdgcn_mfma_f32_16x16x32_bf16(whhA[3][0], hlo, zin[3][j], 0, 0, 0);
        a0 = __builtin_amdgcn_mfma_f32_16x16x32_bf16(whhA[0][1], hhi, a0, 0, 0, 0);
        a1 = __builtin_amdgcn_mfma_f32_16x16x32_bf16(whhA[1][1], hhi, a1, 0, 0, 0);
        a2 = __builtin_amdgcn_mfma_f32_16x16x32_bf16(whhA[2][1], hhi, a2, 0, 0, 0);
        a3 = __builtin_amdgcn_mfma_f32_16x16x32_bf16(whhA[3][1], hhi, a3, 0, 0, 0);
        unsigned hp0 = 0, hp1 = 0;
#pragma unroll
        for (int i = 0; i < 4; ++i) {
            float zi = a0[i], zf = a1[i], zg = a2[i], zo = a3[i];
            float ig = 1.f / (1.f + __expf(-zi));
            float fg = 1.f / (1.f + __expf(-zf));
            float gg = 1.f - 2.f / (__expf(2.f * zg) + 1.f);
            float og = 1.f / (1.f + __expf(-zo));
            float cn = fg * cst[i] + ig * gg;
            cst[i] = cn;
            float th = 1.f - 2.f / (__expf(2.f * cn) + 1.f);
            unsigned hb_ = (unsigned)f2bf(og * th);
            if (i == 0) hp0 = hb_;
            else if (i == 1) hp0 |= hb_ << 16;
            else if (i == 2) hp1 = hb_;
            else hp1 |= hb_ << 16;
        }
        *(uint2*)((char*)ring + ring_addr(slot, lb, (16 * w + lg * 4) * 2)) = make_uint2(hp0, hp1);
        __syncthreads();
    }
}

__global__ __launch_bounds__(256, 1) void lstm_kernel(
    const ushort_t* __restrict__ y,
    const float* __restrict__ whh_f, const float* __restrict__ whh_b,
    const float* __restrict__ wih_f, const float* __restrict__ wih_b,
    const float* __restrict__ bih_f, const float* __restrict__ bhh_f,
    const float* __restrict__ bih_b, const float* __restrict__ bhh_b,
    const float* __restrict__ fc_w, float* __restrict__ em_ws) {
    __shared__ ushort_t ring[8 * 1024];      // 16 KB: 8 slots x [16b][64u] bf16
    int d = blockIdx.x >> 3, bg = blockIdx.x & 7;
    const float* whh = d ? whh_b : whh_f;
    const float* wih = d ? wih_b : wih_f;
    const float* bih = d ? bih_b : bih_f;
    const float* bhh = d ? bhh_b : bhh_f;
    int tid = threadIdx.x;
    int w = tid >> 6, l = tid & 63, lb = l & 15, lg = l >> 4;
    int b = bg * 16 + lb;

    for (int i = tid; i < 4096; i += 256) ((unsigned*)ring)[i] = 0u;

    // A-fragments (row = l&15): rows g*64 + 16w + lb, k = kh*32 + lg*8 + j
    s8v whhA[4][2], wihA[4][2];
#pragma unroll
    for (int g = 0; g < 4; ++g)
#pragma unroll
        for (int kh = 0; kh < 2; ++kh) {
            s8v va, vb;
#pragma unroll
            for (int j = 0; j < 8; ++j) {
                int row = g * 64 + 16 * w + lb;
                int k = kh * 32 + lg * 8 + j;
                va[j] = (short)f2bf(whh[(size_t)row * 64 + k]);
                vb[j] = (short)f2bf(wih[(size_t)row * 64 + k]);
            }
            whhA[g][kh] = va;
            wihA[g][kh] = vb;
        }
    // biases per D cell (row = lg*4+i): unit u = 16w + lg*4 + i
    f4v zbias[4];
#pragma unroll
    for (int g = 0; g < 4; ++g)
#pragma unroll
        for (int i = 0; i < 4; ++i) {
            int u = 16 * w + lg * 4 + i;
            zbias[g][i] = bih[g * 64 + u] + bhh[g * 64 + u];
        }
    // emission A-fragment: rows = class (0,1; pad 2-15 zero), k = unit
    s8v femA[2];
#pragma unroll
    for (int kh = 0; kh < 2; ++kh)
#pragma unroll
        for (int j = 0; j < 8; ++j) {
            int k = kh * 32 + lg * 8 + j;
            femA[kh][j] = (lb < 2) ? (short)f2bf(fc_w[lb * 128 + d * 64 + k]) : (short)0;
        }

    int t0 = d ? (TT - 1) : 0;
    int dstep = d ? -1 : 1;
    const char* ybase = (const char*)y + (size_t)b * TT * 128;
    float2* emv = (float2*)em_ws;

    s8v ybA[4][2], ybB[4][2];
#pragma unroll
    for (int ct = 0; ct < 4; ++ct) {
        int t = t0 + dstep * ct;
        const char* p = ybase + (size_t)t * 128 + lg * 16;
        ybA[ct][0] = *(const s8v*)p;
        ybA[ct][1] = *(const s8v*)(p + 64);
    }
    float cst[4] = {0.f, 0.f, 0.f, 0.f};
    __syncthreads();

    for (int sp = 0; sp < 256; ++sp) {
        lstm_strip<0>(2 * sp, w, lb, lg, b, d, t0, dstep, whhA, wihA, zbias, femA,
                      ybA, ybB, cst, ring, ybase, emv);
        lstm_strip<1>(2 * sp + 1, w, lb, lg, b, d, t0, dstep, whhA, wihA, zbias, femA,
                      ybB, ybA, cst, ring, ybase, emv);
    }
    // emissions for the last strip (slots 4..7)
    if (w == 0) {
#pragma unroll
        for (int ct = 0; ct < 4; ++ct) {
            int slot = 4 + ct;
            s8v hlo = *(const s8v*)((const char*)ring + ring_addr(slot, lb, lg * 16));
            s8v hhi = *(const s8v*)((const char*)ring + ring_addr(slot, lb, 64 + lg * 16));
            f4v a = (f4v){0.f, 0.f, 0.f, 0.f};
            a = __builtin_amdgcn_mfma_f32_16x16x32_bf16(femA[0], hlo, a, 0, 0, 0);
            a = __builtin_amdgcn_mfma_f32_16x16x32_bf16(femA[1], hhi, a, 0, 0, 0);
            if (lg == 0) {
                int t = t0 + dstep * (511 * 4 + ct);
                emv[((size_t)d * TT + t) * BB + b] = make_float2(a[0], a[1]);
            }
        }
    }
}

// ================= Kernel C: CRF via parallel log-semiring scan; block=b, thread=16-step chunk =================
__global__ __launch_bounds__(128) void crf_kernel(
    const float* __restrict__ em_ws, const int* __restrict__ tags,
    const float* __restrict__ fc_b, const float* __restrict__ crf_start,
    const float* __restrict__ crf_end, const float* __restrict__ crf_trans,
    float* __restrict__ nll_ws) {
    int b = blockIdx.x, c = threadIdx.x;
    float fb0 = fc_b[0], fb1 = fc_b[1];
    float t00 = crf_trans[0], t01 = crf_trans[1], t10 = crf_trans[2], t11 = crf_trans[3];
    const float2* p0 = (const float2*)em_ws;
    const float2* p1 = p0 + (size_t)TT * BB;
    const int* tg = tags + (size_t)b * TT;

    int tbeg = 1 + 16 * c;
    int tend = min(TT, tbeg + 16);
    float P00, P01, P10, P11;
    float np = 0.f;
    int tprev = tg[tbeg - 1];
    {
        float2 ea = p0[(size_t)tbeg * BB + b], eb = p1[(size_t)tbeg * BB + b];
        float e0 = ea.x + eb.x + fb0, e1 = ea.y + eb.y + fb1;
        P00 = t00 + e0; P01 = t01 + e1; P10 = t10 + e0; P11 = t11 + e1;
        int tc = tg[tbeg];
        np += (tc ? e1 : e0) + (tprev ? (tc ? t11 : t10) : (tc ? t01 : t00));
        tprev = tc;
    }
    for (int t = tbeg + 1; t < tend; ++t) {
        float2 ea = p0[(size_t)t * BB + b], eb = p1[(size_t)t * BB + b];
        float e0 = ea.x + eb.x + fb0, e1 = ea.y + eb.y + fb1;
        float n00 = lse2(P00 + t00, P01 + t10) + e0;
        float n01 = lse2(P00 + t01, P01 + t11) + e1;
        float n10 = lse2(P10 + t00, P11 + t10) + e0;
        float n11 = lse2(P10 + t01, P11 + t11) + e1;
        P00 = n00; P01 = n01; P10 = n10; P11 = n11;
        int tc = tg[t];
        np += (tc ? e1 : e0) + (tprev ? (tc ? t11 : t10) : (tc ? t01 : t00));
        tprev = tc;
    }
    __shared__ float sP[128][4];
    __shared__ float sN[128];
    sP[c][0] = P00; sP[c][1] = P01; sP[c][2] = P10; sP[c][3] = P11;
    sN[c] = np;
    __syncthreads();
    if (c == 0) {
        float2 ea = p0[b], eb = p1[b];
        float e0 = ea.x + eb.x + fb0, e1 = ea.y + eb.y + fb1;
        float a0 = crf_start[0] + e0, a1 = crf_start[1] + e1;
        float num = tg[0] ? (crf_start[1] + e1) : (crf_start[0] + e0);
        for (int k = 0; k < 128; ++k) {
            float q0 = lse2(a0 + sP[k][0], a1 + sP[k][2]);
            float q1 = lse2(a0 + sP[k][1], a1 + sP[k][3]);
            a0 = q0; a1 = q1;
            num += sN[k];
        }
        num += crf_end[tg[TT - 1]];
        float logZ = lse2(a0 + crf_end[0], a1 + crf_end[1]);
        nll_ws[b] = logZ - num;
    }
}

__global__ __launch_bounds__(128) void sum_kernel(const float* __restrict__ nll_ws,
                                                  float* __restrict__ out) {
    __shared__ float red[BB];
    red[threadIdx.x] = nll_ws[threadIdx.x];
    __syncthreads();
    if (threadIdx.x == 0) {
        float s = 0.f;
        for (int i = 0; i < BB; ++i) s += red[i];
        out[0] = s;
    }
}

extern "C" void kernel_launch(void* const* d_in, const int* in_sizes, int n_in,
                              void* d_out, int out_size, void* d_ws, size_t ws_size,
                              hipStream_t stream) {
    const float* x = (const float*)d_in[0];
    const int* tags = (const int*)d_in[1];
    const float* cw1 = (const float*)d_in[2];
    const float* cb1 = (const float*)d_in[3];
    const float* cwr = (const float*)d_in[4];
    const float* cbr = (const float*)d_in[5];
    const float* bn_g = (const float*)d_in[6];
    const float* bn_b = (const float*)d_in[7];
    const float* bn_m = (const float*)d_in[8];
    const float* bn_v = (const float*)d_in[9];
    const float* wih_f = (const float*)d_in[10];
    const float* whh_f = (const float*)d_in[11];
    const float* bih_f = (const float*)d_in[12];
    const float* bhh_f = (const float*)d_in[13];
    const float* wih_b = (const float*)d_in[14];
    const float* whh_b = (const float*)d_in[15];
    const float* bih_b = (const float*)d_in[16];
    const float* bhh_b = (const float*)d_in[17];
    const float* fc_w = (const float*)d_in[18];
    const float* fc_b = (const float*)d_in[19];
    const float* crf_start = (const float*)d_in[20];
    const float* crf_end = (const float*)d_in[21];
    const float* crf_trans = (const float*)d_in[22];
    float* out = (float*)d_out;

    ushort_t* y = (ushort_t*)d_ws;                                     // 32 MiB
    float* em = (float*)((char*)d_ws + (size_t)BT * 64 * 2);           // 4 MiB
    float* nll = (float*)((char*)d_ws + (size_t)BT * 64 * 2 + (size_t)2 * TT * BB * 2 * 4);

    conv_kernel<<<1024, 256, 0, stream>>>(x, cw1, cb1, cwr, cbr, bn_g, bn_b, bn_m, bn_v, y);
    lstm_kernel<<<16, 256, 0, stream>>>(y, whh_f, whh_b, wih_f, wih_b,
                                        bih_f, bhh_f, bih_b, bhh_b, fc_w, em);
    crf_kernel<<<128, 128, 0, stream>>>(em, tags, fc_b, crf_start, crf_end, crf_trans, nll);
    sum_kernel<<<1, 128, 0, stream>>>(nll, out);
}